// Round 2
// baseline (313.051 us; speedup 1.0000x reference)
//
#include <hip/hip_runtime.h>
#include <math.h>

// Damping: B=32768 samples, N=64, H=256, OFF=2016
//   diag  branch: x -> tanh(Wd1) -> tanh(Wd2) -> Wdo  (64 outputs)
//   off   branch: x -> tanh(Wo1) -> tanh(Wo2) -> Woo  (2016 outputs, strict lower tri)
//   L[s]: diag = xdiag, L[i][j] (j<i) = z[i*(i-1)/2 + j]
//   out  = L (L^T x0)

#define B_TOT 32768
#define NDIM  64
#define HDIM  256
#define OFFD  2016

typedef __bf16 bf16x8 __attribute__((ext_vector_type(8)));
typedef float  f32x4  __attribute__((ext_vector_type(4)));

// ---------------- weight cast (f32 -> bf16), single launch ----------------
__device__ __forceinline__ void cast_range(const float* __restrict__ s,
                                           __bf16* __restrict__ d, int n) {
  int i = blockIdx.x * blockDim.x + threadIdx.x;
  const int stride = gridDim.x * blockDim.x;
  for (; i < n; i += stride) d[i] = (__bf16)s[i];
}

__global__ __launch_bounds__(256) void cast_all_kernel(
    const float* s0, __bf16* d0, int n0,
    const float* s1, __bf16* d1, int n1,
    const float* s2, __bf16* d2, int n2,
    const float* s3, __bf16* d3, int n3,
    const float* s4, __bf16* d4, int n4,
    const float* s5, __bf16* d5, int n5) {
  cast_range(s0, d0, n0);
  cast_range(s1, d1, n1);
  cast_range(s2, d2, n2);
  cast_range(s3, d3, n3);
  cast_range(s4, d4, n4);
  cast_range(s5, d5, n5);
}

// ---------------- helpers ----------------
__device__ __forceinline__ bf16x8 cvt8(const float* __restrict__ p) {
  const float4 u = *(const float4*)p;
  const float4 v = *(const float4*)(p + 4);
  bf16x8 r;
  r[0] = (__bf16)u.x; r[1] = (__bf16)u.y; r[2] = (__bf16)u.z; r[3] = (__bf16)u.w;
  r[4] = (__bf16)v.x; r[5] = (__bf16)v.y; r[6] = (__bf16)v.z; r[7] = (__bf16)v.w;
  return r;
}

// LDS activation tiles use a chunked layout: chunk c = channel/8 (8 bf16 = 16B),
// slot index = c*64 + s  ->  a-frag ds_read_b128 is conflict-free.
__device__ __forceinline__ int lds_slot(int s, int c) { return c * 64 + s; }

// Layer with K=64, A = f32 global rows (converted), out = tanh -> LDS chunks.
__device__ __forceinline__ void layer_k64(const float* __restrict__ xin, int sb,
                                          const __bf16* __restrict__ W,
                                          const float* __restrict__ bias,
                                          bf16x8* buf, int wave, int lr, int lg) {
  __bf16* outh = (__bf16*)buf;
  for (int t = wave; t < 64; t += 8) {
    const int m = t >> 4, n = t & 15;
    f32x4 acc = {0.f, 0.f, 0.f, 0.f};
#pragma unroll
    for (int ks = 0; ks < 2; ++ks) {
      bf16x8 a = cvt8(xin + (size_t)(sb + m * 16 + lr) * NDIM + ks * 32 + lg * 8);
      bf16x8 b = *(const bf16x8*)(W + (n * 16 + lr) * NDIM + ks * 32 + lg * 8);
      acc = __builtin_amdgcn_mfma_f32_16x16x32_bf16(a, b, acc, 0, 0, 0);
    }
    const int ch = n * 16 + lr;
    const float bv = bias[ch];
#pragma unroll
    for (int r = 0; r < 4; ++r) {
      const int s = m * 16 + lg * 4 + r;
      outh[lds_slot(s, ch >> 3) * 8 + (ch & 7)] = (__bf16)tanhf(acc[r] + bv);
    }
  }
}

// Layer with K=256, A = LDS chunks, out = tanh -> LDS chunks.
__device__ __forceinline__ void layer_k256_lds(const bf16x8* src,
                                               const __bf16* __restrict__ W,
                                               const float* __restrict__ bias,
                                               bf16x8* dst, int wave, int lr, int lg) {
  __bf16* outh = (__bf16*)dst;
  for (int t = wave; t < 64; t += 8) {
    const int m = t >> 4, n = t & 15;
    f32x4 acc = {0.f, 0.f, 0.f, 0.f};
#pragma unroll
    for (int ks = 0; ks < 8; ++ks) {
      bf16x8 a = src[lds_slot(m * 16 + lr, ks * 4 + lg)];
      bf16x8 b = *(const bf16x8*)(W + (n * 16 + lr) * HDIM + ks * 32 + lg * 8);
      acc = __builtin_amdgcn_mfma_f32_16x16x32_bf16(a, b, acc, 0, 0, 0);
    }
    const int ch = n * 16 + lr;
    const float bv = bias[ch];
#pragma unroll
    for (int r = 0; r < 4; ++r) {
      const int s = m * 16 + lg * 4 + r;
      outh[lds_slot(s, ch >> 3) * 8 + (ch & 7)] = (__bf16)tanhf(acc[r] + bv);
    }
  }
}

// Layer with K=256, A = LDS chunks, out = tanh -> global bf16 [.,256] row-major.
__device__ __forceinline__ void layer_k256_glob(const bf16x8* src, int sb,
                                                const __bf16* __restrict__ W,
                                                const float* __restrict__ bias,
                                                __bf16* __restrict__ gout,
                                                int wave, int lr, int lg) {
  for (int t = wave; t < 64; t += 8) {
    const int m = t >> 4, n = t & 15;
    f32x4 acc = {0.f, 0.f, 0.f, 0.f};
#pragma unroll
    for (int ks = 0; ks < 8; ++ks) {
      bf16x8 a = src[lds_slot(m * 16 + lr, ks * 4 + lg)];
      bf16x8 b = *(const bf16x8*)(W + (n * 16 + lr) * HDIM + ks * 32 + lg * 8);
      acc = __builtin_amdgcn_mfma_f32_16x16x32_bf16(a, b, acc, 0, 0, 0);
    }
    const int ch = n * 16 + lr;
    const float bv = bias[ch];
#pragma unroll
    for (int r = 0; r < 4; ++r) {
      const int s = m * 16 + lg * 4 + r;
      gout[(size_t)(sb + s) * HDIM + ch] = (__bf16)tanhf(acc[r] + bv);
    }
  }
}

// Output layer diag: K=256, A = LDS chunks, 64 outputs, NO tanh -> global f32.
__device__ __forceinline__ void layer3_diag(const bf16x8* src, int sb,
                                            const __bf16* __restrict__ W,
                                            const float* __restrict__ bias,
                                            float* __restrict__ xd,
                                            int wave, int lr, int lg) {
  for (int t = wave; t < 16; t += 8) {
    const int m = t >> 2, n = t & 3;
    f32x4 acc = {0.f, 0.f, 0.f, 0.f};
#pragma unroll
    for (int ks = 0; ks < 8; ++ks) {
      bf16x8 a = src[lds_slot(m * 16 + lr, ks * 4 + lg)];
      bf16x8 b = *(const bf16x8*)(W + (n * 16 + lr) * HDIM + ks * 32 + lg * 8);
      acc = __builtin_amdgcn_mfma_f32_16x16x32_bf16(a, b, acc, 0, 0, 0);
    }
    const int ch = n * 16 + lr;
    const float bv = bias[ch];
#pragma unroll
    for (int r = 0; r < 4; ++r) {
      const int s = m * 16 + lg * 4 + r;
      xd[(size_t)(sb + s) * NDIM + ch] = acc[r] + bv;
    }
  }
}

// ---------------- K1: both MLP trunks, 64 samples per workgroup ----------------
__global__ __launch_bounds__(512) void trunk_kernel(
    const float* __restrict__ x,
    const __bf16* __restrict__ Wd1, const float* __restrict__ bd1,
    const __bf16* __restrict__ Wd2, const float* __restrict__ bd2,
    const __bf16* __restrict__ Wdo, const float* __restrict__ bdo,
    const __bf16* __restrict__ Wo1, const float* __restrict__ bo1,
    const __bf16* __restrict__ Wo2, const float* __restrict__ bo2,
    __bf16* __restrict__ g2, float* __restrict__ xd) {
  __shared__ bf16x8 buf0[2048];  // 32 KB  (64 samples x 256 ch, chunked)
  __shared__ bf16x8 buf1[2048];  // 32 KB
  const int tid = threadIdx.x;
  const int wave = tid >> 6, lane = tid & 63;
  const int lr = lane & 15, lg = lane >> 4;
  const int sb = blockIdx.x * 64;

  // diag branch
  layer_k64(x, sb, Wd1, bd1, buf0, wave, lr, lg);            // h1 -> buf0
  __syncthreads();
  layer_k256_lds(buf0, Wd2, bd2, buf1, wave, lr, lg);        // h2 -> buf1
  __syncthreads();
  layer3_diag(buf1, sb, Wdo, bdo, xd, wave, lr, lg);         // xdiag -> global
  // off branch (buf0 free after the barrier above)
  layer_k64(x, sb, Wo1, bo1, buf0, wave, lr, lg);            // g1 -> buf0
  __syncthreads();
  layer_k256_glob(buf0, sb, Wo2, bo2, g2, wave, lr, lg);     // g2 -> global bf16
}

// ---------------- K2: Woo GEMM (z in LDS) + triangular apply -----------------
// 32 samples/WG; z[32][2016] bf16 in LDS (126KB) + x0s/ys (16KB) = 145408 B.
#define K2_SMEM (32 * OFFD * 2 + 32 * 64 * 4 * 2)

__global__ __launch_bounds__(512) void offdiag_apply_kernel(
    const __bf16* __restrict__ g2, const __bf16* __restrict__ Woo,
    const float* __restrict__ boo, const float* __restrict__ xd,
    const float* __restrict__ x0, float* __restrict__ out) {
  extern __shared__ char smem[];
  __bf16* zt = (__bf16*)smem;                       // [32][2016]
  float* x0s = (float*)(smem + 32 * OFFD * 2);      // [32][64]
  float* ys  = x0s + 32 * 64;                       // [32][64]

  const int tid = threadIdx.x;
  const int wave = tid >> 6, lane = tid & 63;
  const int lr = lane & 15, lg = lane >> 4;
  const int sb = blockIdx.x * 32;

  // stage x0 tile
  for (int i = tid; i < 32 * 64; i += 512) x0s[i] = x0[(size_t)sb * 64 + i];

  // A-fragments (g2 rows for this sample tile) held in registers for the whole n-loop
  bf16x8 afr[2][8];
#pragma unroll
  for (int m2 = 0; m2 < 2; ++m2)
#pragma unroll
    for (int ks = 0; ks < 8; ++ks)
      afr[m2][ks] =
          *(const bf16x8*)(g2 + (size_t)(sb + m2 * 16 + lr) * HDIM + ks * 32 + lg * 8);

  // GEMM: z[32 x 2016] = G @ Woo^T + boo, written to LDS as bf16
  for (int n = wave; n < OFFD / 16; n += 8) {
    const __bf16* wp = Woo + (size_t)(n * 16 + lr) * HDIM + lg * 8;
    bf16x8 bfr[8];
#pragma unroll
    for (int ks = 0; ks < 8; ++ks) bfr[ks] = *(const bf16x8*)(wp + ks * 32);
    f32x4 acc0 = {0.f, 0.f, 0.f, 0.f}, acc1 = {0.f, 0.f, 0.f, 0.f};
#pragma unroll
    for (int ks = 0; ks < 8; ++ks) {
      acc0 = __builtin_amdgcn_mfma_f32_16x16x32_bf16(afr[0][ks], bfr[ks], acc0, 0, 0, 0);
      acc1 = __builtin_amdgcn_mfma_f32_16x16x32_bf16(afr[1][ks], bfr[ks], acc1, 0, 0, 0);
    }
    const int col = n * 16 + lr;
    const float bv = boo[col];
#pragma unroll
    for (int r = 0; r < 4; ++r) {
      const int s = lg * 4 + r;
      zt[s * OFFD + col] = (__bf16)(acc0[r] + bv);
      zt[(s + 16) * OFFD + col] = (__bf16)(acc1[r] + bv);
    }
  }
  __syncthreads();

  // y[j] = xd[j]*x0[j] + sum_{k>j} z[k(k-1)/2+j] * x0[k]
  const int s = tid >> 4;
  const int jb = tid & 15;
  const float* x0r = x0s + s * 64;
  const __bf16* zr = zt + s * OFFD;
#pragma unroll
  for (int jj = 0; jj < 4; ++jj) {
    const int j = jb + 16 * jj;
    float acc = xd[(size_t)(sb + s) * 64 + j] * x0r[j];
    for (int k = j + 1; k < 64; ++k)
      acc += (float)zr[k * (k - 1) / 2 + j] * x0r[k];
    ys[s * 64 + j] = acc;
  }
  __syncthreads();

  // D[i] = xd[i]*y[i] + sum_{j<i} z[i(i-1)/2+j] * y[j]
  const float* yr = ys + s * 64;
#pragma unroll
  for (int ii = 0; ii < 4; ++ii) {
    const int i = jb + 16 * ii;
    float acc = xd[(size_t)(sb + s) * 64 + i] * yr[i];
    const int base = i * (i - 1) / 2;
    for (int j = 0; j < i; ++j)
      acc += (float)zr[base + j] * yr[j];
    out[(size_t)(sb + s) * 64 + i] = acc;
  }
}

// ---------------- launch ----------------
extern "C" void kernel_launch(void* const* d_in, const int* in_sizes, int n_in,
                              void* d_out, int out_size, void* d_ws, size_t ws_size,
                              hipStream_t stream) {
  const float* x   = (const float*)d_in[0];
  const float* Wd1 = (const float*)d_in[1];
  const float* bd1 = (const float*)d_in[2];
  const float* Wd2 = (const float*)d_in[3];
  const float* bd2 = (const float*)d_in[4];
  const float* Wdo = (const float*)d_in[5];
  const float* bdo = (const float*)d_in[6];
  const float* Wo1 = (const float*)d_in[7];
  const float* bo1 = (const float*)d_in[8];
  const float* Wo2 = (const float*)d_in[9];
  const float* bo2 = (const float*)d_in[10];
  const float* Woo = (const float*)d_in[11];
  const float* boo = (const float*)d_in[12];
  float* out = (float*)d_out;

  char* ws = (char*)d_ws;
  __bf16* Wd1b = (__bf16*)(ws + 0);         //  32768 B
  __bf16* Wd2b = (__bf16*)(ws + 32768);     // 131072 B
  __bf16* Wdob = (__bf16*)(ws + 163840);    //  32768 B
  __bf16* Wo1b = (__bf16*)(ws + 196608);    //  32768 B
  __bf16* Wo2b = (__bf16*)(ws + 229376);    // 131072 B
  __bf16* Woob = (__bf16*)(ws + 360448);    // 1032192 B
  __bf16* g2   = (__bf16*)(ws + 1392640);   // B*256*2 = 16777216 B
  float*  xdp  = (float*)(ws + 18169856);   // B*64*4  =  8388608 B (end 26558464)

  cast_all_kernel<<<512, 256, 0, stream>>>(
      Wd1, Wd1b, HDIM * NDIM,
      Wd2, Wd2b, HDIM * HDIM,
      Wdo, Wdob, NDIM * HDIM,
      Wo1, Wo1b, HDIM * NDIM,
      Wo2, Wo2b, HDIM * HDIM,
      Woo, Woob, OFFD * HDIM);

  trunk_kernel<<<B_TOT / 64, 512, 0, stream>>>(x, Wd1b, bd1, Wd2b, bd2, Wdob, bdo,
                                               Wo1b, bo1, Wo2b, bo2, g2, xdp);

  hipFuncSetAttribute((const void*)offdiag_apply_kernel,
                      hipFuncAttributeMaxDynamicSharedMemorySize, K2_SMEM);
  offdiag_apply_kernel<<<B_TOT / 32, 512, K2_SMEM, stream>>>(g2, Woob, boo, xdp, x, out);
}

// Round 4
// 307.620 us; speedup vs baseline: 1.0177x; 1.0177x over previous
//
#include <hip/hip_runtime.h>
#include <math.h>

// Damping: B=32768 samples, N=64, H=256, OFF=2016
//   diag branch: x -> tanh(Wd1) -> tanh(Wd2) -> Wdo  (64 outputs)
//   off  branch: x -> tanh(Wo1) -> tanh(Wo2) -> Woo  (2016 outputs, strict lower tri)
//   out = L (L^T x0),  L diag = xdiag, L[i][j] (j<i) = z[i*(i-1)/2+j]

#define B_TOT 32768
#define NDIM  64
#define HDIM  256
#define OFFD  2016
#define ZSTR  2020   // padded zt row stride (words%32==18 -> lg-groups hit distinct octets)

typedef __bf16 bf16x8 __attribute__((ext_vector_type(8)));
typedef float  f32x4  __attribute__((ext_vector_type(4)));

__device__ __forceinline__ float fast_tanh(float x) {
  // branch-free tanh: 1 - 2/(exp(2x)+1); exact at +-inf, ~1e-6 rel err (bf16-safe)
  float e = __expf(2.f * x);
  return 1.f - 2.f * __builtin_amdgcn_rcpf(e + 1.f);
}

__device__ __forceinline__ float lane_bcast(float v, int l) {
  return __uint_as_float(__builtin_amdgcn_readlane(__float_as_uint(v), l));
}

// ---------------- weight cast (f32 -> bf16), single launch ----------------
__device__ __forceinline__ void cast_range(const float* __restrict__ s,
                                           __bf16* __restrict__ d, int n) {
  int i = blockIdx.x * blockDim.x + threadIdx.x;
  const int stride = gridDim.x * blockDim.x;
  for (; i < n; i += stride) d[i] = (__bf16)s[i];
}

__global__ __launch_bounds__(256) void cast_all_kernel(
    const float* s0, __bf16* d0, int n0,
    const float* s1, __bf16* d1, int n1,
    const float* s2, __bf16* d2, int n2,
    const float* s3, __bf16* d3, int n3,
    const float* s4, __bf16* d4, int n4,
    const float* s5, __bf16* d5, int n5) {
  cast_range(s0, d0, n0);
  cast_range(s1, d1, n1);
  cast_range(s2, d2, n2);
  cast_range(s3, d3, n3);
  cast_range(s4, d4, n4);
  cast_range(s5, d5, n5);
}

// ---------------- helpers ----------------
__device__ __forceinline__ bf16x8 cvt8(const float* __restrict__ p) {
  const float4 u = *(const float4*)p;
  const float4 v = *(const float4*)(p + 4);
  bf16x8 r;
  r[0] = (__bf16)u.x; r[1] = (__bf16)u.y; r[2] = (__bf16)u.z; r[3] = (__bf16)u.w;
  r[4] = (__bf16)v.x; r[5] = (__bf16)v.y; r[6] = (__bf16)v.z; r[7] = (__bf16)v.w;
  return r;
}

// LDS activation tiles: chunk c = channel/8 (16B), slot = c*64 + sample
__device__ __forceinline__ int lds_slot(int s, int c) { return c * 64 + s; }

// Layer K=64, A = f32 global rows, out = tanh -> LDS chunks.
__device__ __forceinline__ void layer_k64(const float* __restrict__ xin, int sb,
                                          const __bf16* __restrict__ W,
                                          const float* __restrict__ bias,
                                          bf16x8* buf, int wave, int lr, int lg) {
  __bf16* outh = (__bf16*)buf;
  for (int t = wave; t < 64; t += 8) {
    const int m = t >> 4, n = t & 15;
    f32x4 acc = {0.f, 0.f, 0.f, 0.f};
#pragma unroll
    for (int ks = 0; ks < 2; ++ks) {
      bf16x8 a = cvt8(xin + (size_t)(sb + m * 16 + lr) * NDIM + ks * 32 + lg * 8);
      bf16x8 b = *(const bf16x8*)(W + (n * 16 + lr) * NDIM + ks * 32 + lg * 8);
      acc = __builtin_amdgcn_mfma_f32_16x16x32_bf16(a, b, acc, 0, 0, 0);
    }
    const int ch = n * 16 + lr;
    const float bv = bias[ch];
#pragma unroll
    for (int r = 0; r < 4; ++r) {
      const int s = m * 16 + lg * 4 + r;
      outh[lds_slot(s, ch >> 3) * 8 + (ch & 7)] = (__bf16)fast_tanh(acc[r] + bv);
    }
  }
}

// Layer K=256, A = LDS chunks, out = tanh -> LDS chunks.  B-frag prefetched.
__device__ __forceinline__ void layer_k256_lds(const bf16x8* src,
                                               const __bf16* __restrict__ W,
                                               const float* __restrict__ bias,
                                               bf16x8* dst, int wave, int lr, int lg) {
  __bf16* outh = (__bf16*)dst;
  bf16x8 bfr[8];
  {
    const __bf16* wp = W + (wave * 16 + lr) * HDIM + lg * 8;  // first t==wave -> n=wave
#pragma unroll
    for (int ks = 0; ks < 8; ++ks) bfr[ks] = *(const bf16x8*)(wp + ks * 32);
  }
  for (int t = wave; t < 64; t += 8) {
    const int m = t >> 4, n = t & 15;
    bf16x8 bnx[8];
    const int tn = t + 8;
    if (tn < 64) {
      const __bf16* wp = W + ((tn & 15) * 16 + lr) * HDIM + lg * 8;
#pragma unroll
      for (int ks = 0; ks < 8; ++ks) bnx[ks] = *(const bf16x8*)(wp + ks * 32);
    }
    f32x4 acc = {0.f, 0.f, 0.f, 0.f};
#pragma unroll
    for (int ks = 0; ks < 8; ++ks) {
      bf16x8 a = src[lds_slot(m * 16 + lr, ks * 4 + lg)];
      acc = __builtin_amdgcn_mfma_f32_16x16x32_bf16(a, bfr[ks], acc, 0, 0, 0);
    }
    const int ch = n * 16 + lr;
    const float bv = bias[ch];
#pragma unroll
    for (int r = 0; r < 4; ++r) {
      const int s = m * 16 + lg * 4 + r;
      outh[lds_slot(s, ch >> 3) * 8 + (ch & 7)] = (__bf16)fast_tanh(acc[r] + bv);
    }
#pragma unroll
    for (int ks = 0; ks < 8; ++ks) bfr[ks] = bnx[ks];
  }
}

// Layer K=256, A = LDS chunks, out = tanh -> global bf16 [.,256].  Prefetched.
__device__ __forceinline__ void layer_k256_glob(const bf16x8* src, int sb,
                                                const __bf16* __restrict__ W,
                                                const float* __restrict__ bias,
                                                __bf16* __restrict__ gout,
                                                int wave, int lr, int lg) {
  bf16x8 bfr[8];
  {
    const __bf16* wp = W + (wave * 16 + lr) * HDIM + lg * 8;
#pragma unroll
    for (int ks = 0; ks < 8; ++ks) bfr[ks] = *(const bf16x8*)(wp + ks * 32);
  }
  for (int t = wave; t < 64; t += 8) {
    const int m = t >> 4, n = t & 15;
    bf16x8 bnx[8];
    const int tn = t + 8;
    if (tn < 64) {
      const __bf16* wp = W + ((tn & 15) * 16 + lr) * HDIM + lg * 8;
#pragma unroll
      for (int ks = 0; ks < 8; ++ks) bnx[ks] = *(const bf16x8*)(wp + ks * 32);
    }
    f32x4 acc = {0.f, 0.f, 0.f, 0.f};
#pragma unroll
    for (int ks = 0; ks < 8; ++ks) {
      bf16x8 a = src[lds_slot(m * 16 + lr, ks * 4 + lg)];
      acc = __builtin_amdgcn_mfma_f32_16x16x32_bf16(a, bfr[ks], acc, 0, 0, 0);
    }
    const int ch = n * 16 + lr;
    const float bv = bias[ch];
#pragma unroll
    for (int r = 0; r < 4; ++r) {
      const int s = m * 16 + lg * 4 + r;
      gout[(size_t)(sb + s) * HDIM + ch] = (__bf16)fast_tanh(acc[r] + bv);
    }
#pragma unroll
    for (int ks = 0; ks < 8; ++ks) bfr[ks] = bnx[ks];
  }
}

// Output layer diag: K=256, 64 outputs, NO tanh -> global f32.
__device__ __forceinline__ void layer3_diag(const bf16x8* src, int sb,
                                            const __bf16* __restrict__ W,
                                            const float* __restrict__ bias,
                                            float* __restrict__ xd,
                                            int wave, int lr, int lg) {
  for (int t = wave; t < 16; t += 8) {
    const int m = t >> 2, n = t & 3;
    f32x4 acc = {0.f, 0.f, 0.f, 0.f};
#pragma unroll
    for (int ks = 0; ks < 8; ++ks) {
      bf16x8 a = src[lds_slot(m * 16 + lr, ks * 4 + lg)];
      bf16x8 b = *(const bf16x8*)(W + (n * 16 + lr) * HDIM + ks * 32 + lg * 8);
      acc = __builtin_amdgcn_mfma_f32_16x16x32_bf16(a, b, acc, 0, 0, 0);
    }
    const int ch = n * 16 + lr;
    const float bv = bias[ch];
#pragma unroll
    for (int r = 0; r < 4; ++r) {
      const int s = m * 16 + lg * 4 + r;
      xd[(size_t)(sb + s) * NDIM + ch] = acc[r] + bv;
    }
  }
}

// ---------------- K1: both MLP trunks, 64 samples per workgroup ----------------
__global__ __launch_bounds__(512, 4) void trunk_kernel(
    const float* __restrict__ x,
    const __bf16* __restrict__ Wd1, const float* __restrict__ bd1,
    const __bf16* __restrict__ Wd2, const float* __restrict__ bd2,
    const __bf16* __restrict__ Wdo, const float* __restrict__ bdo,
    const __bf16* __restrict__ Wo1, const float* __restrict__ bo1,
    const __bf16* __restrict__ Wo2, const float* __restrict__ bo2,
    __bf16* __restrict__ g2, float* __restrict__ xd) {
  __shared__ bf16x8 buf0[2048];  // 32 KB
  __shared__ bf16x8 buf1[2048];  // 32 KB
  const int tid = threadIdx.x;
  const int wave = tid >> 6, lane = tid & 63;
  const int lr = lane & 15, lg = lane >> 4;
  const int sb = blockIdx.x * 64;

  layer_k64(x, sb, Wd1, bd1, buf0, wave, lr, lg);            // h1 -> buf0
  __syncthreads();
  layer_k256_lds(buf0, Wd2, bd2, buf1, wave, lr, lg);        // h2 -> buf1
  __syncthreads();
  layer3_diag(buf1, sb, Wdo, bdo, xd, wave, lr, lg);         // xdiag -> global
  layer_k64(x, sb, Wo1, bo1, buf0, wave, lr, lg);            // g1 -> buf0
  __syncthreads();
  layer_k256_glob(buf0, sb, Wo2, bo2, g2, wave, lr, lg);     // g2 -> global bf16
}

// ---------------- K2: Woo GEMM (z in LDS) + triangular apply -----------------
// 32 samples/WG, 1024 threads (16 waves -> 50% occupancy at 1 WG/CU).
// zt [32][ZSTR] bf16 (129.3 KB) + x0s [32][64] f32 (8 KB) = 137472 B.
#define K2_SMEM (32 * ZSTR * 2 + 32 * 64 * 4)

__global__ __launch_bounds__(1024, 4) void offdiag_apply_kernel(
    const __bf16* __restrict__ g2, const __bf16* __restrict__ Woo,
    const float* __restrict__ boo, const float* __restrict__ xd,
    const float* __restrict__ x0, float* __restrict__ out) {
  extern __shared__ char smem[];
  __bf16* zt = (__bf16*)smem;                   // [32][ZSTR]
  float* x0s = (float*)(smem + 32 * ZSTR * 2);  // [32][64]

  const int tid = threadIdx.x;
  const int wave = tid >> 6, lane = tid & 63;
  const int lr = lane & 15, lg = lane >> 4;
  const int sb = blockIdx.x * 32;

  for (int i = tid; i < 32 * 64; i += 1024) x0s[i] = x0[(size_t)sb * 64 + i];

  // A-fragments (g2 rows, 32 samples) in registers for the whole n-loop
  bf16x8 afr[2][8];
#pragma unroll
  for (int m2 = 0; m2 < 2; ++m2)
#pragma unroll
    for (int ks = 0; ks < 8; ++ks)
      afr[m2][ks] =
          *(const bf16x8*)(g2 + (size_t)(sb + m2 * 16 + lr) * HDIM + ks * 32 + lg * 8);

  // GEMM: z[32 x 2016] = G @ Woo^T + boo -> LDS bf16 (padded rows)
  for (int n = wave; n < OFFD / 16; n += 16) {
    const __bf16* wp = Woo + (size_t)(n * 16 + lr) * HDIM + lg * 8;
    bf16x8 bfr[8];
#pragma unroll
    for (int ks = 0; ks < 8; ++ks) bfr[ks] = *(const bf16x8*)(wp + ks * 32);
    f32x4 acc0 = {0.f, 0.f, 0.f, 0.f}, acc1 = {0.f, 0.f, 0.f, 0.f};
#pragma unroll
    for (int ks = 0; ks < 8; ++ks) {
      acc0 = __builtin_amdgcn_mfma_f32_16x16x32_bf16(afr[0][ks], bfr[ks], acc0, 0, 0, 0);
      acc1 = __builtin_amdgcn_mfma_f32_16x16x32_bf16(afr[1][ks], bfr[ks], acc1, 0, 0, 0);
    }
    const int col = n * 16 + lr;
    const float bv = boo[col];
#pragma unroll
    for (int r = 0; r < 4; ++r) {
      const int s = lg * 4 + r;
      zt[s * ZSTR + col] = (__bf16)(acc0[r] + bv);
      zt[(s + 16) * ZSTR + col] = (__bf16)(acc1[r] + bv);
    }
  }
  __syncthreads();

  // Apply: wave w handles samples 2w, 2w+1.  lane = output index.
  // Uniform-k loops: per-instruction LDS reads are 64 consecutive bf16 (no conflicts);
  // x0[k], y[j] broadcast via v_readlane.
#pragma unroll
  for (int ss = 0; ss < 2; ++ss) {
    const int s = wave * 2 + ss;
    const __bf16* zrow = zt + s * ZSTR;
    const float x0v = x0s[s * 64 + lane];
    const float xdv = xd[(size_t)(sb + s) * 64 + lane];

    // pass 1: y_j = xd_j*x0_j + sum_{k>j} z[k(k-1)/2+j] * x0_k
    float y = xdv * x0v;
    int base = 0;
    for (int k = 1; k < 64; ++k) {
      base += k - 1;  // k(k-1)/2
      const float zv = (float)zrow[base + lane];
      const float xk = lane_bcast(x0v, k);
      y += (lane < k) ? zv * xk : 0.f;
    }

    // pass 2: D_i = xd_i*y_i + sum_{j<i} z[i(i-1)/2+j] * y_j
    const int ibase = (lane * (lane - 1)) >> 1;
    float D = xdv * y;
    for (int j = 0; j < 63; ++j) {
      const float zv = (float)zrow[ibase + j];
      const float yj = lane_bcast(y, j);
      D += (lane > j) ? zv * yj : 0.f;
    }
    out[(size_t)(sb + s) * 64 + lane] = D;
  }
}

// ---------------- launch ----------------
extern "C" void kernel_launch(void* const* d_in, const int* in_sizes, int n_in,
                              void* d_out, int out_size, void* d_ws, size_t ws_size,
                              hipStream_t stream) {
  const float* x   = (const float*)d_in[0];
  const float* Wd1 = (const float*)d_in[1];
  const float* bd1 = (const float*)d_in[2];
  const float* Wd2 = (const float*)d_in[3];
  const float* bd2 = (const float*)d_in[4];
  const float* Wdo = (const float*)d_in[5];
  const float* bdo = (const float*)d_in[6];
  const float* Wo1 = (const float*)d_in[7];
  const float* bo1 = (const float*)d_in[8];
  const float* Wo2 = (const float*)d_in[9];
  const float* bo2 = (const float*)d_in[10];
  const float* Woo = (const float*)d_in[11];
  const float* boo = (const float*)d_in[12];
  float* out = (float*)d_out;

  char* ws = (char*)d_ws;
  __bf16* Wd1b = (__bf16*)(ws + 0);         //  32768 B
  __bf16* Wd2b = (__bf16*)(ws + 32768);     // 131072 B
  __bf16* Wdob = (__bf16*)(ws + 163840);    //  32768 B
  __bf16* Wo1b = (__bf16*)(ws + 196608);    //  32768 B
  __bf16* Wo2b = (__bf16*)(ws + 229376);    // 131072 B
  __bf16* Woob = (__bf16*)(ws + 360448);    // 1032192 B
  __bf16* g2   = (__bf16*)(ws + 1392640);   // B*256*2 = 16777216 B
  float*  xdp  = (float*)(ws + 18169856);   // B*64*4  =  8388608 B

  cast_all_kernel<<<512, 256, 0, stream>>>(
      Wd1, Wd1b, HDIM * NDIM,
      Wd2, Wd2b, HDIM * HDIM,
      Wdo, Wdob, NDIM * HDIM,
      Wo1, Wo1b, HDIM * NDIM,
      Wo2, Wo2b, HDIM * HDIM,
      Woo, Woob, OFFD * HDIM);

  trunk_kernel<<<B_TOT / 64, 512, 0, stream>>>(x, Wd1b, bd1, Wd2b, bd2, Wdob, bdo,
                                               Wo1b, bo1, Wo2b, bo2, g2, xdp);

  hipFuncSetAttribute((const void*)offdiag_apply_kernel,
                      hipFuncAttributeMaxDynamicSharedMemorySize, K2_SMEM);
  offdiag_apply_kernel<<<B_TOT / 32, 1024, K2_SMEM, stream>>>(g2, Woob, boo, xdp, x, out);
}